// Round 1
// baseline (356.339 us; speedup 1.0000x reference)
//
#include <hip/hip_runtime.h>
#include <math.h>

#define B_ 2
#define S_ 2048
#define E_ 768
#define H_ 12
#define D_ 64
#define M_TOT (B_*S_)   // 4096

typedef __attribute__((ext_vector_type(8))) short s16x8;
typedef __attribute__((ext_vector_type(4))) float f32x4;

__device__ __forceinline__ unsigned short f2bf(float f) {
  union { float f; unsigned u; } v; v.f = f;
  unsigned r = (v.u + 0x7fffu + ((v.u >> 16) & 1u)) >> 16;
  return (unsigned short)r;
}

__device__ __forceinline__ int swz(int r) { return ((r >> 3) ^ r) & 7; }

__device__ __forceinline__ void gload_lds16(const unsigned short* g, unsigned short* l) {
  __builtin_amdgcn_global_load_lds(
      (const __attribute__((address_space(1))) void*)g,
      (__attribute__((address_space(3))) void*)l, 16, 0, 0);
}

// ---------------- transpose + fp32->bf16 convert: in [R][C] f32 -> out [C][R] bf16
__global__ __launch_bounds__(256) void tconv_kernel(const float* __restrict__ in,
                                                    unsigned short* __restrict__ out,
                                                    int R, int C) {
  __shared__ float tile[32][33];
  int c0 = blockIdx.x * 32, r0 = blockIdx.y * 32;
  int t = threadIdx.x;
  int cl = t & 31, rl = t >> 5;          // rl: 0..7
  #pragma unroll
  for (int p = 0; p < 4; ++p)
    tile[rl + p*8][cl] = in[(size_t)(r0 + rl + p*8)*C + c0 + cl];
  __syncthreads();
  int rl2 = t & 31, cl2 = t >> 5;
  #pragma unroll
  for (int p = 0; p < 4; ++p)
    out[(size_t)(c0 + cl2 + p*8)*R + r0 + rl2] = f2bf(tile[rl2][cl2 + p*8]);
}

// ---------------- layernorm: x f32 [rows][768] -> out bf16
__global__ __launch_bounds__(64) void ln_kernel(const float* __restrict__ x,
                                                const float* __restrict__ g,
                                                const float* __restrict__ b,
                                                unsigned short* __restrict__ out) {
  int row = blockIdx.x;
  int lane = threadIdx.x;     // 64
  const float* xr = x + (size_t)row * E_;
  float4 v[3];
  float s = 0.f, sq = 0.f;
  #pragma unroll
  for (int p = 0; p < 3; ++p) {
    v[p] = *reinterpret_cast<const float4*>(xr + p*256 + lane*4);
    s  += v[p].x + v[p].y + v[p].z + v[p].w;
    sq += v[p].x*v[p].x + v[p].y*v[p].y + v[p].z*v[p].z + v[p].w*v[p].w;
  }
  #pragma unroll
  for (int off = 32; off; off >>= 1) {
    s  += __shfl_xor(s,  off, 64);
    sq += __shfl_xor(sq, off, 64);
  }
  float mu  = s * (1.f/E_);
  float var = sq * (1.f/E_) - mu*mu;
  float rstd = rsqrtf(var + 1e-5f);
  unsigned short* orow = out + (size_t)row * E_;
  #pragma unroll
  for (int p = 0; p < 3; ++p) {
    int c = p*256 + lane*4;
    float4 gg = *reinterpret_cast<const float4*>(g + c);
    float4 bb = *reinterpret_cast<const float4*>(b + c);
    ushort4 o;
    o.x = f2bf((v[p].x-mu)*rstd*gg.x + bb.x);
    o.y = f2bf((v[p].y-mu)*rstd*gg.y + bb.y);
    o.z = f2bf((v[p].z-mu)*rstd*gg.z + bb.z);
    o.w = f2bf((v[p].w-mu)*rstd*gg.w + bb.w);
    *reinterpret_cast<ushort4*>(orow + c) = o;
  }
}

// ---------------- GEMM: C[M][N] = A[M][K](bf16) @ Wt[N][K]^T(bf16) + bias
// MODE 0: store bf16 ; MODE 1: store f32 + residual ; MODE 2: gelu -> bf16
template<int MODE>
__global__ __launch_bounds__(256) void gemm_kernel(
    const unsigned short* __restrict__ A,
    const unsigned short* __restrict__ Wt,
    const float* __restrict__ bias,
    const float* __restrict__ res,
    unsigned short* __restrict__ outb,
    float* __restrict__ outf,
    int M, int N, int K)
{
  __shared__ __align__(16) unsigned short As[128*64];
  __shared__ __align__(16) unsigned short Ws[128*64];
  int m0 = blockIdx.y * 128, n0 = blockIdx.x * 128;
  int t = threadIdx.x, lane = t & 63, w = t >> 6;
  f32x4 acc[4][4] = {};
  int KT = K >> 6;

  auto stage = [&](int kt) {
    int k0 = kt << 6;
    #pragma unroll
    for (int p = 0; p < 4; ++p) {
      int off = p*2048 + w*512 + lane*8;      // linear elem offset in 128x64 tile
      int r = off >> 6;                       // tile row
      int slot = (off & 63) >> 3;             // 8-elem slot within row
      int k8 = slot ^ swz(r);                 // pre-swizzled source column block
      gload_lds16(A  + (size_t)(m0 + r)*K + k0 + k8*8, As + p*2048 + w*512);
      gload_lds16(Wt + (size_t)(n0 + r)*K + k0 + k8*8, Ws + p*2048 + w*512);
    }
  };

  int wm = (w >> 1) * 64, wn = (w & 1) * 64;
  int li = lane & 15, g = lane >> 4;

  stage(0);
  for (int kt = 0; kt < KT; ++kt) {
    __syncthreads();
    #pragma unroll
    for (int kk = 0; kk < 2; ++kk) {
      s16x8 af[4], bf[4];
      int k8 = kk*4 + g;
      #pragma unroll
      for (int mi = 0; mi < 4; ++mi) {
        int r = wm + mi*16 + li;
        af[mi] = *reinterpret_cast<const s16x8*>(As + r*64 + ((k8 ^ swz(r)) << 3));
      }
      #pragma unroll
      for (int ni = 0; ni < 4; ++ni) {
        int r = wn + ni*16 + li;
        bf[ni] = *reinterpret_cast<const s16x8*>(Ws + r*64 + ((k8 ^ swz(r)) << 3));
      }
      #pragma unroll
      for (int mi = 0; mi < 4; ++mi)
        #pragma unroll
        for (int ni = 0; ni < 4; ++ni)
          acc[mi][ni] = __builtin_amdgcn_mfma_f32_16x16x32_bf16(af[mi], bf[ni], acc[mi][ni], 0, 0, 0);
    }
    __syncthreads();
    if (kt + 1 < KT) stage(kt + 1);
  }

  // epilogue
  #pragma unroll
  for (int mi = 0; mi < 4; ++mi) {
    #pragma unroll
    for (int j = 0; j < 4; ++j) {
      int row = m0 + wm + mi*16 + g*4 + j;
      #pragma unroll
      for (int ni = 0; ni < 4; ++ni) {
        int col = n0 + wn + ni*16 + li;
        float v = acc[mi][ni][j] + bias[col];
        size_t idx = (size_t)row * N + col;
        if (MODE == 0) {
          outb[idx] = f2bf(v);
        } else if (MODE == 1) {
          outf[idx] = v + res[idx];
        } else {
          float gv = 0.5f * v * (1.f + erff(v * 0.70710678118f));
          outb[idx] = f2bf(gv);
        }
      }
    }
  }
}

// ---------------- causal flash attention, no scale.
// qkv bf16 [B*S][2304]  (q|k|v each 768 = 12 heads * 64)
// out bf16 [B*S][768]
__global__ __launch_bounds__(64) void attn_kernel(const unsigned short* __restrict__ qkv,
                                                  unsigned short* __restrict__ out) {
  int qt = blockIdx.x;              // q tile of 16 rows
  int bh = blockIdx.y;
  int b = bh / H_, h = bh % H_;
  int lane = threadIdx.x;
  int li = lane & 15, g = lane >> 4;
  const size_t rs = 3*E_;           // 2304
  const unsigned short* base = qkv + (size_t)b * S_ * rs;
  __shared__ __align__(16) unsigned short Vt[64*32];  // [d][kv]
  __shared__ __align__(16) unsigned short P[16*32];   // [q][kv]

  s16x8 qf[2];
  int qrow = qt*16 + li;
  #pragma unroll
  for (int f = 0; f < 2; ++f)
    qf[f] = *reinterpret_cast<const s16x8*>(base + (size_t)qrow*rs + h*64 + f*32 + g*8);

  float m[4], l[4];
  f32x4 o[4] = {};
  #pragma unroll
  for (int j = 0; j < 4; ++j) { m[j] = -1e30f; l[j] = 0.f; }

  int nkv = (qt*16 + 15) / 32 + 1;
  for (int tt = 0; tt < nkv; ++tt) {
    int kv0 = tt * 32;
    // ---- scores S[16q][32kv] = Q Kt  (two 16-col halves)
    float pm[2][4];
    #pragma unroll
    for (int nh = 0; nh < 2; ++nh) {
      int krow = kv0 + nh*16 + li;
      s16x8 kf0 = *reinterpret_cast<const s16x8*>(base + (size_t)krow*rs + E_ + h*64 + g*8);
      s16x8 kf1 = *reinterpret_cast<const s16x8*>(base + (size_t)krow*rs + E_ + h*64 + 32 + g*8);
      f32x4 z = {};
      z = __builtin_amdgcn_mfma_f32_16x16x32_bf16(qf[0], kf0, z, 0, 0, 0);
      z = __builtin_amdgcn_mfma_f32_16x16x32_bf16(qf[1], kf1, z, 0, 0, 0);
      #pragma unroll
      for (int j = 0; j < 4; ++j) {
        int kvc = kv0 + nh*16 + li;
        int qr  = qt*16 + g*4 + j;
        pm[nh][j] = (kvc <= qr) ? z[j] : -1e30f;
      }
    }
    // ---- online softmax (rows live in 16-lane groups)
    #pragma unroll
    for (int j = 0; j < 4; ++j) {
      float tm = fmaxf(pm[0][j], pm[1][j]);
      #pragma unroll
      for (int off = 8; off; off >>= 1) tm = fmaxf(tm, __shfl_xor(tm, off, 16));
      float mnew = fmaxf(m[j], tm);
      float sc = __expf(m[j] - mnew);
      float ps = 0.f;
      #pragma unroll
      for (int nh = 0; nh < 2; ++nh) {
        pm[nh][j] = __expf(pm[nh][j] - mnew);
        ps += pm[nh][j];
      }
      #pragma unroll
      for (int off = 8; off; off >>= 1) ps += __shfl_xor(ps, off, 16);
      l[j] = l[j]*sc + ps;
      m[j] = mnew;
      #pragma unroll
      for (int nc = 0; nc < 4; ++nc) o[nc][j] *= sc;
    }
    // ---- stash P (bf16) and V^T in LDS
    #pragma unroll
    for (int nh = 0; nh < 2; ++nh)
      #pragma unroll
      for (int j = 0; j < 4; ++j)
        P[(g*4 + j)*32 + nh*16 + li] = f2bf(pm[nh][j]);
    #pragma unroll
    for (int p = 0; p < 4; ++p) {
      int kv = lane >> 1, d8 = (lane & 1) + p*2;
      s16x8 vv = *reinterpret_cast<const s16x8*>(base + (size_t)(kv0+kv)*rs + 2*E_ + h*64 + d8*8);
      #pragma unroll
      for (int i = 0; i < 8; ++i)
        Vt[(d8*8 + i)*32 + kv] = (unsigned short)vv[i];
    }
    __syncthreads();
    // ---- PV
    s16x8 pf = *reinterpret_cast<const s16x8*>(P + li*32 + g*8);
    #pragma unroll
    for (int nc = 0; nc < 4; ++nc) {
      s16x8 vf = *reinterpret_cast<const s16x8*>(Vt + (nc*16 + li)*32 + g*8);
      o[nc] = __builtin_amdgcn_mfma_f32_16x16x32_bf16(pf, vf, o[nc], 0, 0, 0);
    }
    __syncthreads();
  }
  float inv[4];
  #pragma unroll
  for (int j = 0; j < 4; ++j) inv[j] = 1.f / l[j];
  #pragma unroll
  for (int nc = 0; nc < 4; ++nc)
    #pragma unroll
    for (int j = 0; j < 4; ++j)
      out[(size_t)(b*S_ + qt*16 + g*4 + j)*E_ + h*64 + nc*16 + li] = f2bf(o[nc][j] * inv[j]);
}

extern "C" void kernel_launch(void* const* d_in, const int* in_sizes, int n_in,
                              void* d_out, int out_size, void* d_ws, size_t ws_size,
                              hipStream_t stream) {
  const float* x       = (const float*)d_in[0];
  const float* ln1g    = (const float*)d_in[1];
  const float* ln1b    = (const float*)d_in[2];
  const float* w_attn  = (const float*)d_in[3];
  const float* b_attn  = (const float*)d_in[4];
  const float* w_aproj = (const float*)d_in[5];
  const float* b_aproj = (const float*)d_in[6];
  const float* ln2g    = (const float*)d_in[7];
  const float* ln2b    = (const float*)d_in[8];
  const float* w_fc    = (const float*)d_in[9];
  const float* b_fc    = (const float*)d_in[10];
  const float* w_fproj = (const float*)d_in[11];
  const float* b_fproj = (const float*)d_in[12];
  float* out = (float*)d_out;

  char* ws = (char*)d_ws;
  unsigned short* h1       = (unsigned short*)(ws + 0);          // 4096x768 bf16
  unsigned short* qkv      = (unsigned short*)(ws + 6291456);    // 4096x2304 bf16
  unsigned short* attno    = (unsigned short*)(ws + 25165824);   // 4096x768 bf16
  float*          x2       = (float*)(ws + 31457280);            // 4096x768 f32
  unsigned short* h2       = (unsigned short*)(ws + 44040192);   // 4096x768 bf16
  unsigned short* h3       = (unsigned short*)(ws + 50331648);   // 4096x3072 bf16
  unsigned short* wt_attn  = (unsigned short*)(ws + 75497472);   // 2304x768 bf16
  unsigned short* wt_aproj = (unsigned short*)(ws + 79036416);   // 768x768
  unsigned short* wt_fc    = (unsigned short*)(ws + 80216064);   // 3072x768
  unsigned short* wt_fproj = (unsigned short*)(ws + 84934656);   // 768x3072

  // weight transpose+convert: [K][N] f32 -> [N][K] bf16
  tconv_kernel<<<dim3(2304/32,  768/32), 256, 0, stream>>>(w_attn,  wt_attn,  768, 2304);
  tconv_kernel<<<dim3( 768/32,  768/32), 256, 0, stream>>>(w_aproj, wt_aproj, 768,  768);
  tconv_kernel<<<dim3(3072/32,  768/32), 256, 0, stream>>>(w_fc,    wt_fc,    768, 3072);
  tconv_kernel<<<dim3( 768/32, 3072/32), 256, 0, stream>>>(w_fproj, wt_fproj, 3072, 768);

  // LN1
  ln_kernel<<<dim3(M_TOT), dim3(64), 0, stream>>>(x, ln1g, ln1b, h1);
  // QKV
  gemm_kernel<0><<<dim3(2304/128, M_TOT/128), 256, 0, stream>>>(h1, wt_attn, b_attn, nullptr, qkv, nullptr, M_TOT, 2304, 768);
  // attention
  attn_kernel<<<dim3(S_/16, B_*H_), dim3(64), 0, stream>>>(qkv, attno);
  // attn proj + residual -> x2 (f32)
  gemm_kernel<1><<<dim3(768/128, M_TOT/128), 256, 0, stream>>>(attno, wt_aproj, b_aproj, x, nullptr, x2, M_TOT, 768, 768);
  // LN2
  ln_kernel<<<dim3(M_TOT), dim3(64), 0, stream>>>(x2, ln2g, ln2b, h2);
  // FC + gelu
  gemm_kernel<2><<<dim3(3072/128, M_TOT/128), 256, 0, stream>>>(h2, wt_fc, b_fc, nullptr, h3, nullptr, M_TOT, 3072, 768);
  // fproj + residual -> out (f32)
  gemm_kernel<1><<<dim3(768/128, M_TOT/128), 256, 0, stream>>>(h3, wt_fproj, b_fproj, x2, nullptr, out, M_TOT, 768, 3072);
}

// Round 2
// 287.078 us; speedup vs baseline: 1.2413x; 1.2413x over previous
//
#include <hip/hip_runtime.h>
#include <math.h>

#define B_ 2
#define S_ 2048
#define E_ 768
#define H_ 12
#define D_ 64
#define M_TOT (B_*S_)   // 4096

typedef __attribute__((ext_vector_type(8))) short s16x8;
typedef __attribute__((ext_vector_type(4))) float f32x4;

__device__ __forceinline__ unsigned short f2bf(float f) {
  union { float f; unsigned u; } v; v.f = f;
  unsigned r = (v.u + 0x7fffu + ((v.u >> 16) & 1u)) >> 16;
  return (unsigned short)r;
}

__device__ __forceinline__ int swz(int r) { return ((r >> 3) ^ r) & 7; }

__device__ __forceinline__ void gload_lds16(const unsigned short* g, unsigned short* l) {
  __builtin_amdgcn_global_load_lds(
      (const __attribute__((address_space(1))) void*)g,
      (__attribute__((address_space(3))) void*)l, 16, 0, 0);
}

// ---------------- transpose + fp32->bf16 convert: in [R][C] f32 -> out [C][R] bf16
__global__ __launch_bounds__(256) void tconv_kernel(const float* __restrict__ in,
                                                    unsigned short* __restrict__ out,
                                                    int R, int C) {
  __shared__ float tile[32][33];
  int c0 = blockIdx.x * 32, r0 = blockIdx.y * 32;
  int t = threadIdx.x;
  int cl = t & 31, rl = t >> 5;          // rl: 0..7
  #pragma unroll
  for (int p = 0; p < 4; ++p)
    tile[rl + p*8][cl] = in[(size_t)(r0 + rl + p*8)*C + c0 + cl];
  __syncthreads();
  int rl2 = t & 31, cl2 = t >> 5;
  #pragma unroll
  for (int p = 0; p < 4; ++p)
    out[(size_t)(c0 + cl2 + p*8)*R + r0 + rl2] = f2bf(tile[rl2][cl2 + p*8]);
}

// ---------------- layernorm: x f32 [rows][768] -> out bf16
__global__ __launch_bounds__(64) void ln_kernel(const float* __restrict__ x,
                                                const float* __restrict__ g,
                                                const float* __restrict__ b,
                                                unsigned short* __restrict__ out) {
  int row = blockIdx.x;
  int lane = threadIdx.x;     // 64
  const float* xr = x + (size_t)row * E_;
  float4 v[3];
  float s = 0.f, sq = 0.f;
  #pragma unroll
  for (int p = 0; p < 3; ++p) {
    v[p] = *reinterpret_cast<const float4*>(xr + p*256 + lane*4);
    s  += v[p].x + v[p].y + v[p].z + v[p].w;
    sq += v[p].x*v[p].x + v[p].y*v[p].y + v[p].z*v[p].z + v[p].w*v[p].w;
  }
  #pragma unroll
  for (int off = 32; off; off >>= 1) {
    s  += __shfl_xor(s,  off, 64);
    sq += __shfl_xor(sq, off, 64);
  }
  float mu  = s * (1.f/E_);
  float var = sq * (1.f/E_) - mu*mu;
  float rstd = rsqrtf(var + 1e-5f);
  unsigned short* orow = out + (size_t)row * E_;
  #pragma unroll
  for (int p = 0; p < 3; ++p) {
    int c = p*256 + lane*4;
    float4 gg = *reinterpret_cast<const float4*>(g + c);
    float4 bb = *reinterpret_cast<const float4*>(b + c);
    ushort4 o;
    o.x = f2bf((v[p].x-mu)*rstd*gg.x + bb.x);
    o.y = f2bf((v[p].y-mu)*rstd*gg.y + bb.y);
    o.z = f2bf((v[p].z-mu)*rstd*gg.z + bb.z);
    o.w = f2bf((v[p].w-mu)*rstd*gg.w + bb.w);
    *reinterpret_cast<ushort4*>(orow + c) = o;
  }
}

// ---------------- GEMM: C[M][N] = A[M][K](bf16) @ Wt[N][K]^T(bf16) + bias
// MODE 0: store bf16 ; MODE 1: store f32 + residual ; MODE 2: gelu -> bf16
template<int MODE>
__global__ __launch_bounds__(256) void gemm_kernel(
    const unsigned short* __restrict__ A,
    const unsigned short* __restrict__ Wt,
    const float* __restrict__ bias,
    const float* __restrict__ res,
    unsigned short* __restrict__ outb,
    float* __restrict__ outf,
    int M, int N, int K)
{
  __shared__ __align__(16) unsigned short As[128*64];
  __shared__ __align__(16) unsigned short Ws[128*64];
  int m0 = blockIdx.y * 128, n0 = blockIdx.x * 128;
  int t = threadIdx.x, lane = t & 63, w = t >> 6;
  f32x4 acc[4][4] = {};
  int KT = K >> 6;

  auto stage = [&](int kt) {
    int k0 = kt << 6;
    #pragma unroll
    for (int p = 0; p < 4; ++p) {
      int off = p*2048 + w*512 + lane*8;      // linear elem offset in 128x64 tile
      int r = off >> 6;                       // tile row
      int slot = (off & 63) >> 3;             // 8-elem slot within row
      int k8 = slot ^ swz(r);                 // pre-swizzled source column block
      gload_lds16(A  + (size_t)(m0 + r)*K + k0 + k8*8, As + p*2048 + w*512);
      gload_lds16(Wt + (size_t)(n0 + r)*K + k0 + k8*8, Ws + p*2048 + w*512);
    }
  };

  int wm = (w >> 1) * 64, wn = (w & 1) * 64;
  int li = lane & 15, g = lane >> 4;

  stage(0);
  for (int kt = 0; kt < KT; ++kt) {
    __syncthreads();
    #pragma unroll
    for (int kk = 0; kk < 2; ++kk) {
      s16x8 af[4], bf[4];
      int k8 = kk*4 + g;
      #pragma unroll
      for (int mi = 0; mi < 4; ++mi) {
        int r = wm + mi*16 + li;
        af[mi] = *reinterpret_cast<const s16x8*>(As + r*64 + ((k8 ^ swz(r)) << 3));
      }
      #pragma unroll
      for (int ni = 0; ni < 4; ++ni) {
        int r = wn + ni*16 + li;
        bf[ni] = *reinterpret_cast<const s16x8*>(Ws + r*64 + ((k8 ^ swz(r)) << 3));
      }
      #pragma unroll
      for (int mi = 0; mi < 4; ++mi)
        #pragma unroll
        for (int ni = 0; ni < 4; ++ni)
          acc[mi][ni] = __builtin_amdgcn_mfma_f32_16x16x32_bf16(af[mi], bf[ni], acc[mi][ni], 0, 0, 0);
    }
    __syncthreads();
    if (kt + 1 < KT) stage(kt + 1);
  }

  // epilogue
  #pragma unroll
  for (int mi = 0; mi < 4; ++mi) {
    #pragma unroll
    for (int j = 0; j < 4; ++j) {
      int row = m0 + wm + mi*16 + g*4 + j;
      #pragma unroll
      for (int ni = 0; ni < 4; ++ni) {
        int col = n0 + wn + ni*16 + li;
        float v = acc[mi][ni][j] + bias[col];
        size_t idx = (size_t)row * N + col;
        if (MODE == 0) {
          outb[idx] = f2bf(v);
        } else if (MODE == 1) {
          outf[idx] = v + res[idx];
        } else {
          float gv = 0.5f * v * (1.f + erff(v * 0.70710678118f));
          outb[idx] = f2bf(gv);
        }
      }
    }
  }
}

// ---------------- causal flash attention v2, no scale.
// 4 waves/block, Q-tile 64 rows (16/wave), KV-tile 64.
// qkv bf16 [B*S][2304]  (q|k|v each 768 = 12 heads * 64)
// out bf16 [B*S][768]
__global__ __launch_bounds__(256) void attn_kernel(const unsigned short* __restrict__ qkv,
                                                   unsigned short* __restrict__ out) {
  __shared__ __align__(16) unsigned short Ks[64*64];     // [kv][d] xor-swizzled slots
  __shared__ __align__(16) unsigned short Vt[64*72];     // [d][kv] padded
  __shared__ __align__(16) unsigned short Pl[4*16*72];   // per-wave P [16][72] padded

  int qt = gridDim.x - 1 - blockIdx.x;   // big tiles first (tail-fill)
  int bh = blockIdx.y;
  int b = bh / H_, h = bh % H_;
  int t = threadIdx.x, lane = t & 63, w = t >> 6;
  int li = lane & 15, g = lane >> 4;
  const size_t rs = 3*E_;                // 2304
  const unsigned short* base  = qkv + (size_t)b * S_ * rs;
  const unsigned short* kbase = base + E_   + h*64;
  const unsigned short* vbase = base + 2*E_ + h*64;
  unsigned short* Pw = Pl + w*16*72;

  int q0w = qt*64 + w*16;                // this wave's q rows
  s16x8 qf[2];
  #pragma unroll
  for (int f = 0; f < 2; ++f)
    qf[f] = *reinterpret_cast<const s16x8*>(base + (size_t)(q0w+li)*rs + h*64 + f*32 + g*8);

  float m[4], l[4];
  f32x4 o[4] = {};
  #pragma unroll
  for (int j = 0; j < 4; ++j) { m[j] = -1e30f; l[j] = 0.f; }

  // V staging coords (reg-transpose path)
  int vkv = t >> 2, vd0 = (t & 3) * 16;

  for (int tt = 0; tt <= qt; ++tt) {
    int kv0 = tt * 64;
    // ---- stage K via global_load_lds (pre-swizzled source)
    #pragma unroll
    for (int p = 0; p < 2; ++p) {
      int off = p*2048 + w*512 + lane*8;
      int r = off >> 6;
      int slot = (off & 63) >> 3;
      gload_lds16(kbase + (size_t)(kv0 + r)*rs + ((slot ^ (r & 7)) << 3),
                  Ks + p*2048 + w*512);
    }
    // ---- stage V^T via registers (transpose into padded LDS)
    #pragma unroll
    for (int half = 0; half < 2; ++half) {
      s16x8 vv = *reinterpret_cast<const s16x8*>(vbase + (size_t)(kv0+vkv)*rs + vd0 + half*8);
      #pragma unroll
      for (int i = 0; i < 8; ++i)
        Vt[(vd0 + half*8 + i)*72 + vkv] = (unsigned short)vv[i];
    }
    __syncthreads();

    // ---- QK^T: S[16q][64kv]
    float pm[4][4];
    #pragma unroll
    for (int nh = 0; nh < 4; ++nh) {
      int r = nh*16 + li;
      int sw = r & 7;
      s16x8 kf0 = *reinterpret_cast<const s16x8*>(Ks + r*64 + ((g       ^ sw) << 3));
      s16x8 kf1 = *reinterpret_cast<const s16x8*>(Ks + r*64 + (((4 + g) ^ sw) << 3));
      f32x4 z = {};
      z = __builtin_amdgcn_mfma_f32_16x16x32_bf16(qf[0], kf0, z, 0, 0, 0);
      z = __builtin_amdgcn_mfma_f32_16x16x32_bf16(qf[1], kf1, z, 0, 0, 0);
      if (tt == qt) {   // diagonal tile: causal mask
        #pragma unroll
        for (int j = 0; j < 4; ++j) {
          int kvc = kv0 + nh*16 + li;
          int qr  = q0w + g*4 + j;
          pm[nh][j] = (kvc <= qr) ? z[j] : -1e30f;
        }
      } else {
        #pragma unroll
        for (int j = 0; j < 4; ++j) pm[nh][j] = z[j];
      }
    }

    // ---- online softmax (rows live in 16-lane groups)
    #pragma unroll
    for (int j = 0; j < 4; ++j) {
      float tm = fmaxf(fmaxf(pm[0][j], pm[1][j]), fmaxf(pm[2][j], pm[3][j]));
      #pragma unroll
      for (int off = 8; off; off >>= 1) tm = fmaxf(tm, __shfl_xor(tm, off, 16));
      float mnew = fmaxf(m[j], tm);
      float sc = __expf(m[j] - mnew);
      float ps = 0.f;
      #pragma unroll
      for (int nh = 0; nh < 4; ++nh) {
        pm[nh][j] = __expf(pm[nh][j] - mnew);
        ps += pm[nh][j];
      }
      #pragma unroll
      for (int off = 8; off; off >>= 1) ps += __shfl_xor(ps, off, 16);
      l[j] = l[j]*sc + ps;
      m[j] = mnew;
      #pragma unroll
      for (int nc = 0; nc < 4; ++nc) o[nc][j] *= sc;
    }

    // ---- P -> LDS (per-wave, bf16)
    #pragma unroll
    for (int nh = 0; nh < 4; ++nh)
      #pragma unroll
      for (int j = 0; j < 4; ++j)
        Pw[(g*4 + j)*72 + nh*16 + li] = f2bf(pm[nh][j]);

    // ---- PV: o[16q][64d] += P[16q][64kv] x V[64kv][64d]
    #pragma unroll
    for (int kk = 0; kk < 2; ++kk) {
      s16x8 pf = *reinterpret_cast<const s16x8*>(Pw + li*72 + kk*32 + g*8);
      #pragma unroll
      for (int nc = 0; nc < 4; ++nc) {
        s16x8 vf = *reinterpret_cast<const s16x8*>(Vt + (nc*16 + li)*72 + kk*32 + g*8);
        o[nc] = __builtin_amdgcn_mfma_f32_16x16x32_bf16(pf, vf, o[nc], 0, 0, 0);
      }
    }
    __syncthreads();
  }

  float inv[4];
  #pragma unroll
  for (int j = 0; j < 4; ++j) inv[j] = 1.f / l[j];
  #pragma unroll
  for (int nc = 0; nc < 4; ++nc)
    #pragma unroll
    for (int j = 0; j < 4; ++j)
      out[(size_t)(b*S_ + q0w + g*4 + j)*E_ + h*64 + nc*16 + li] = f2bf(o[nc][j] * inv[j]);
}

extern "C" void kernel_launch(void* const* d_in, const int* in_sizes, int n_in,
                              void* d_out, int out_size, void* d_ws, size_t ws_size,
                              hipStream_t stream) {
  const float* x       = (const float*)d_in[0];
  const float* ln1g    = (const float*)d_in[1];
  const float* ln1b    = (const float*)d_in[2];
  const float* w_attn  = (const float*)d_in[3];
  const float* b_attn  = (const float*)d_in[4];
  const float* w_aproj = (const float*)d_in[5];
  const float* b_aproj = (const float*)d_in[6];
  const float* ln2g    = (const float*)d_in[7];
  const float* ln2b    = (const float*)d_in[8];
  const float* w_fc    = (const float*)d_in[9];
  const float* b_fc    = (const float*)d_in[10];
  const float* w_fproj = (const float*)d_in[11];
  const float* b_fproj = (const float*)d_in[12];
  float* out = (float*)d_out;

  char* ws = (char*)d_ws;
  unsigned short* h1       = (unsigned short*)(ws + 0);          // 4096x768 bf16
  unsigned short* qkv      = (unsigned short*)(ws + 6291456);    // 4096x2304 bf16
  unsigned short* attno    = (unsigned short*)(ws + 25165824);   // 4096x768 bf16
  float*          x2       = (float*)(ws + 31457280);            // 4096x768 f32
  unsigned short* h2       = (unsigned short*)(ws + 44040192);   // 4096x768 bf16
  unsigned short* h3       = (unsigned short*)(ws + 50331648);   // 4096x3072 bf16
  unsigned short* wt_attn  = (unsigned short*)(ws + 75497472);   // 2304x768 bf16
  unsigned short* wt_aproj = (unsigned short*)(ws + 79036416);   // 768x768
  unsigned short* wt_fc    = (unsigned short*)(ws + 80216064);   // 3072x768
  unsigned short* wt_fproj = (unsigned short*)(ws + 84934656);   // 768x3072

  // weight transpose+convert: [K][N] f32 -> [N][K] bf16
  tconv_kernel<<<dim3(2304/32,  768/32), 256, 0, stream>>>(w_attn,  wt_attn,  768, 2304);
  tconv_kernel<<<dim3( 768/32,  768/32), 256, 0, stream>>>(w_aproj, wt_aproj, 768,  768);
  tconv_kernel<<<dim3(3072/32,  768/32), 256, 0, stream>>>(w_fc,    wt_fc,    768, 3072);
  tconv_kernel<<<dim3( 768/32, 3072/32), 256, 0, stream>>>(w_fproj, wt_fproj, 3072, 768);

  // LN1
  ln_kernel<<<dim3(M_TOT), dim3(64), 0, stream>>>(x, ln1g, ln1b, h1);
  // QKV
  gemm_kernel<0><<<dim3(2304/128, M_TOT/128), 256, 0, stream>>>(h1, wt_attn, b_attn, nullptr, qkv, nullptr, M_TOT, 2304, 768);
  // attention
  attn_kernel<<<dim3(S_/64, B_*H_), dim3(256), 0, stream>>>(qkv, attno);
  // attn proj + residual -> x2 (f32)
  gemm_kernel<1><<<dim3(768/128, M_TOT/128), 256, 0, stream>>>(attno, wt_aproj, b_aproj, x, nullptr, x2, M_TOT, 768, 768);
  // LN2
  ln_kernel<<<dim3(M_TOT), dim3(64), 0, stream>>>(x2, ln2g, ln2b, h2);
  // FC + gelu
  gemm_kernel<2><<<dim3(3072/128, M_TOT/128), 256, 0, stream>>>(h2, wt_fc, b_fc, nullptr, h3, nullptr, M_TOT, 3072, 768);
  // fproj + residual -> out (f32)
  gemm_kernel<1><<<dim3(768/128, M_TOT/128), 256, 0, stream>>>(h3, wt_fproj, b_fproj, x2, nullptr, out, M_TOT, 768, 3072);
}

// Round 3
// 274.309 us; speedup vs baseline: 1.2990x; 1.0465x over previous
//
#include <hip/hip_runtime.h>
#include <math.h>

#define B_ 2
#define S_ 2048
#define E_ 768
#define H_ 12
#define D_ 64
#define M_TOT (B_*S_)   // 4096

typedef __attribute__((ext_vector_type(8))) short s16x8;
typedef __attribute__((ext_vector_type(4))) float f32x4;

__device__ __forceinline__ unsigned short f2bf(float f) {
  union { float f; unsigned u; } v; v.f = f;
  unsigned r = (v.u + 0x7fffu + ((v.u >> 16) & 1u)) >> 16;
  return (unsigned short)r;
}

__device__ __forceinline__ int swz(int r) { return ((r >> 3) ^ r) & 7; }

__device__ __forceinline__ void gload_lds16(const unsigned short* g, unsigned short* l) {
  __builtin_amdgcn_global_load_lds(
      (const __attribute__((address_space(1))) void*)g,
      (__attribute__((address_space(3))) void*)l, 16, 0, 0);
}

// ---------------- transpose + fp32->bf16 convert: in [R][C] f32 -> out [C][R] bf16
__global__ __launch_bounds__(256) void tconv_kernel(const float* __restrict__ in,
                                                    unsigned short* __restrict__ out,
                                                    int R, int C) {
  __shared__ float tile[32][33];
  int c0 = blockIdx.x * 32, r0 = blockIdx.y * 32;
  int t = threadIdx.x;
  int cl = t & 31, rl = t >> 5;          // rl: 0..7
  #pragma unroll
  for (int p = 0; p < 4; ++p)
    tile[rl + p*8][cl] = in[(size_t)(r0 + rl + p*8)*C + c0 + cl];
  __syncthreads();
  int rl2 = t & 31, cl2 = t >> 5;
  #pragma unroll
  for (int p = 0; p < 4; ++p)
    out[(size_t)(c0 + cl2 + p*8)*R + r0 + rl2] = f2bf(tile[rl2][cl2 + p*8]);
}

// ---------------- V transpose: qkv bf16 [B*S][2304] -> vt [ (b*H+h)*64+d ][ S ] bf16
__global__ __launch_bounds__(256) void vtrans_kernel(const unsigned short* __restrict__ qkv,
                                                     unsigned short* __restrict__ vt) {
  __shared__ unsigned short tile[32][33];
  int s0 = blockIdx.x * 32;
  int by = blockIdx.y;                // bh*2 + d-half
  int bh = by >> 1, dh = by & 1;
  int b = bh / H_, h = bh % H_;
  int t = threadIdx.x;
  const unsigned short* src = qkv + (size_t)(b*S_)*2304 + 2*E_ + h*64 + dh*32;
  int srow = t >> 3, dq = t & 7;      // load: 32 s-rows x 32 d
  ushort4 v = *reinterpret_cast<const ushort4*>(src + (size_t)(s0 + srow)*2304 + dq*4);
  tile[srow][dq*4+0] = v.x; tile[srow][dq*4+1] = v.y;
  tile[srow][dq*4+2] = v.z; tile[srow][dq*4+3] = v.w;
  __syncthreads();
  int drow = t >> 3, sq = t & 7;      // store: 32 d-rows x 32 s
  ushort4 o;
  o.x = tile[sq*4+0][drow]; o.y = tile[sq*4+1][drow];
  o.z = tile[sq*4+2][drow]; o.w = tile[sq*4+3][drow];
  *reinterpret_cast<ushort4*>(vt + (size_t)(bh*64 + dh*32 + drow)*S_ + s0 + sq*4) = o;
}

// ---------------- layernorm: x f32 [rows][768] -> out bf16
__global__ __launch_bounds__(64) void ln_kernel(const float* __restrict__ x,
                                                const float* __restrict__ g,
                                                const float* __restrict__ b,
                                                unsigned short* __restrict__ out) {
  int row = blockIdx.x;
  int lane = threadIdx.x;     // 64
  const float* xr = x + (size_t)row * E_;
  float4 v[3];
  float s = 0.f, sq = 0.f;
  #pragma unroll
  for (int p = 0; p < 3; ++p) {
    v[p] = *reinterpret_cast<const float4*>(xr + p*256 + lane*4);
    s  += v[p].x + v[p].y + v[p].z + v[p].w;
    sq += v[p].x*v[p].x + v[p].y*v[p].y + v[p].z*v[p].z + v[p].w*v[p].w;
  }
  #pragma unroll
  for (int off = 32; off; off >>= 1) {
    s  += __shfl_xor(s,  off, 64);
    sq += __shfl_xor(sq, off, 64);
  }
  float mu  = s * (1.f/E_);
  float var = sq * (1.f/E_) - mu*mu;
  float rstd = rsqrtf(var + 1e-5f);
  unsigned short* orow = out + (size_t)row * E_;
  #pragma unroll
  for (int p = 0; p < 3; ++p) {
    int c = p*256 + lane*4;
    float4 gg = *reinterpret_cast<const float4*>(g + c);
    float4 bb = *reinterpret_cast<const float4*>(b + c);
    ushort4 o;
    o.x = f2bf((v[p].x-mu)*rstd*gg.x + bb.x);
    o.y = f2bf((v[p].y-mu)*rstd*gg.y + bb.y);
    o.z = f2bf((v[p].z-mu)*rstd*gg.z + bb.z);
    o.w = f2bf((v[p].w-mu)*rstd*gg.w + bb.w);
    *reinterpret_cast<ushort4*>(orow + c) = o;
  }
}

// ---------------- GEMM: C[M][N] = A[M][K](bf16) @ Wt[N][K]^T(bf16) + bias
// MODE 0: store bf16 ; MODE 1: store f32 + residual ; MODE 2: gelu -> bf16
template<int MODE>
__global__ __launch_bounds__(256) void gemm_kernel(
    const unsigned short* __restrict__ A,
    const unsigned short* __restrict__ Wt,
    const float* __restrict__ bias,
    const float* __restrict__ res,
    unsigned short* __restrict__ outb,
    float* __restrict__ outf,
    int M, int N, int K)
{
  __shared__ __align__(16) unsigned short As[128*64];
  __shared__ __align__(16) unsigned short Ws[128*64];
  int m0 = blockIdx.y * 128, n0 = blockIdx.x * 128;
  int t = threadIdx.x, lane = t & 63, w = t >> 6;
  f32x4 acc[4][4] = {};
  int KT = K >> 6;

  auto stage = [&](int kt) {
    int k0 = kt << 6;
    #pragma unroll
    for (int p = 0; p < 4; ++p) {
      int off = p*2048 + w*512 + lane*8;      // linear elem offset in 128x64 tile
      int r = off >> 6;                       // tile row
      int slot = (off & 63) >> 3;             // 8-elem slot within row
      int k8 = slot ^ swz(r);                 // pre-swizzled source column block
      gload_lds16(A  + (size_t)(m0 + r)*K + k0 + k8*8, As + p*2048 + w*512);
      gload_lds16(Wt + (size_t)(n0 + r)*K + k0 + k8*8, Ws + p*2048 + w*512);
    }
  };

  int wm = (w >> 1) * 64, wn = (w & 1) * 64;
  int li = lane & 15, g = lane >> 4;

  stage(0);
  for (int kt = 0; kt < KT; ++kt) {
    __syncthreads();
    #pragma unroll
    for (int kk = 0; kk < 2; ++kk) {
      s16x8 af[4], bf[4];
      int k8 = kk*4 + g;
      #pragma unroll
      for (int mi = 0; mi < 4; ++mi) {
        int r = wm + mi*16 + li;
        af[mi] = *reinterpret_cast<const s16x8*>(As + r*64 + ((k8 ^ swz(r)) << 3));
      }
      #pragma unroll
      for (int ni = 0; ni < 4; ++ni) {
        int r = wn + ni*16 + li;
        bf[ni] = *reinterpret_cast<const s16x8*>(Ws + r*64 + ((k8 ^ swz(r)) << 3));
      }
      #pragma unroll
      for (int mi = 0; mi < 4; ++mi)
        #pragma unroll
        for (int ni = 0; ni < 4; ++ni)
          acc[mi][ni] = __builtin_amdgcn_mfma_f32_16x16x32_bf16(af[mi], bf[ni], acc[mi][ni], 0, 0, 0);
    }
    __syncthreads();
    if (kt + 1 < KT) stage(kt + 1);
  }

  // epilogue
  #pragma unroll
  for (int mi = 0; mi < 4; ++mi) {
    #pragma unroll
    for (int j = 0; j < 4; ++j) {
      int row = m0 + wm + mi*16 + g*4 + j;
      #pragma unroll
      for (int ni = 0; ni < 4; ++ni) {
        int col = n0 + wn + ni*16 + li;
        float v = acc[mi][ni][j] + bias[col];
        size_t idx = (size_t)row * N + col;
        if (MODE == 0) {
          outb[idx] = f2bf(v);
        } else if (MODE == 1) {
          outf[idx] = v + res[idx];
        } else {
          float gv = 0.5f * v * (1.f + erff(v * 0.70710678118f));
          outb[idx] = f2bf(gv);
        }
      }
    }
  }
}

// ---------------- causal flash attention v3, no scale.
// 4 waves/block, Q-tile 64 rows (16/wave), KV-tile 64, double-buffered K/V^T
// staged via global_load_lds; V pre-transposed globally.
__global__ __launch_bounds__(256) void attn_kernel(const unsigned short* __restrict__ qkv,
                                                   const unsigned short* __restrict__ vtg,
                                                   unsigned short* __restrict__ out) {
  __shared__ __align__(16) unsigned short Ks[2][64*64];   // [kv][d] swizzled
  __shared__ __align__(16) unsigned short Vs[2][64*64];   // [d][kv] swizzled
  __shared__ __align__(16) unsigned short Pl[4][16*72];   // per-wave P [16][72]

  int qt = gridDim.x - 1 - blockIdx.x;   // big tiles first (tail-fill)
  int bh = blockIdx.y;
  int b = bh / H_, h = bh % H_;
  int t = threadIdx.x, lane = t & 63, w = t >> 6;
  int li = lane & 15, g = lane >> 4;
  const size_t rs = 3*E_;                // 2304
  const unsigned short* base  = qkv + (size_t)b * S_ * rs;
  const unsigned short* kbase = base + E_ + h*64;
  const unsigned short* vbase = vtg + (size_t)bh * 64 * S_;   // rows d, cols s
  unsigned short* Pw = Pl[w];

  int q0w = qt*64 + w*16;                // this wave's q rows
  s16x8 qf[2];
  #pragma unroll
  for (int f = 0; f < 2; ++f)
    qf[f] = *reinterpret_cast<const s16x8*>(base + (size_t)(q0w+li)*rs + h*64 + f*32 + g*8);

  float m[4], l[4];
  f32x4 o[4] = {};
  #pragma unroll
  for (int j = 0; j < 4; ++j) { m[j] = -1e30f; l[j] = 0.f; }

  auto stage = [&](int tt, int buf) {
    int kv0 = tt * 64;
    #pragma unroll
    for (int p = 0; p < 2; ++p) {
      int off = p*2048 + w*512 + lane*8;
      int r = off >> 6;
      int slot = (off & 63) >> 3;
      gload_lds16(kbase + (size_t)(kv0 + r)*rs + ((slot ^ (r & 7)) << 3),
                  &Ks[buf][p*2048 + w*512]);
      gload_lds16(vbase + (size_t)r*S_ + kv0 + ((slot ^ (r & 7)) << 3),
                  &Vs[buf][p*2048 + w*512]);
    }
  };

  stage(0, 0);
  __syncthreads();

  for (int tt = 0; tt <= qt; ++tt) {
    int cur = tt & 1;
    if (tt < qt) stage(tt + 1, cur ^ 1);   // async prefetch overlaps compute

    // ---- QK^T: S[16q][64kv]
    float pm[4][4];
    #pragma unroll
    for (int nh = 0; nh < 4; ++nh) {
      int r = nh*16 + li;
      int sw = r & 7;
      s16x8 kf0 = *reinterpret_cast<const s16x8*>(&Ks[cur][r*64 + ((g       ^ sw) << 3)]);
      s16x8 kf1 = *reinterpret_cast<const s16x8*>(&Ks[cur][r*64 + (((4 + g) ^ sw) << 3)]);
      f32x4 z = {};
      z = __builtin_amdgcn_mfma_f32_16x16x32_bf16(qf[0], kf0, z, 0, 0, 0);
      z = __builtin_amdgcn_mfma_f32_16x16x32_bf16(qf[1], kf1, z, 0, 0, 0);
      if (tt == qt) {   // diagonal tile: causal mask
        #pragma unroll
        for (int j = 0; j < 4; ++j) {
          int kvc = tt*64 + nh*16 + li;
          int qr  = q0w + g*4 + j;
          pm[nh][j] = (kvc <= qr) ? z[j] : -1e30f;
        }
      } else {
        #pragma unroll
        for (int j = 0; j < 4; ++j) pm[nh][j] = z[j];
      }
    }

    // ---- online softmax (rows live in 16-lane groups)
    #pragma unroll
    for (int j = 0; j < 4; ++j) {
      float tm = fmaxf(fmaxf(pm[0][j], pm[1][j]), fmaxf(pm[2][j], pm[3][j]));
      #pragma unroll
      for (int off = 8; off; off >>= 1) tm = fmaxf(tm, __shfl_xor(tm, off, 16));
      float mnew = fmaxf(m[j], tm);
      float sc = __expf(m[j] - mnew);
      float ps = 0.f;
      #pragma unroll
      for (int nh = 0; nh < 4; ++nh) {
        pm[nh][j] = __expf(pm[nh][j] - mnew);
        ps += pm[nh][j];
      }
      #pragma unroll
      for (int off = 8; off; off >>= 1) ps += __shfl_xor(ps, off, 16);
      l[j] = l[j]*sc + ps;
      m[j] = mnew;
      #pragma unroll
      for (int nc = 0; nc < 4; ++nc) o[nc][j] *= sc;
    }

    // ---- P -> LDS (per-wave, bf16; in-wave LDS ordering, no barrier needed)
    #pragma unroll
    for (int nh = 0; nh < 4; ++nh)
      #pragma unroll
      for (int j = 0; j < 4; ++j)
        Pw[(g*4 + j)*72 + nh*16 + li] = f2bf(pm[nh][j]);

    // ---- PV: o[16q][64d] += P[16q][64kv] x Vt[64d][64kv]^T
    #pragma unroll
    for (int kk = 0; kk < 2; ++kk) {
      s16x8 pf = *reinterpret_cast<const s16x8*>(Pw + li*72 + kk*32 + g*8);
      #pragma unroll
      for (int nc = 0; nc < 4; ++nc) {
        int r = nc*16 + li;
        s16x8 vf = *reinterpret_cast<const s16x8*>(&Vs[cur][r*64 + (((kk*4 + g) ^ (r & 7)) << 3)]);
        o[nc] = __builtin_amdgcn_mfma_f32_16x16x32_bf16(pf, vf, o[nc], 0, 0, 0);
      }
    }
    __syncthreads();   // drains vmcnt (prefetch) + lgkm; one barrier per tile
  }

  float inv[4];
  #pragma unroll
  for (int j = 0; j < 4; ++j) inv[j] = 1.f / l[j];
  #pragma unroll
  for (int nc = 0; nc < 4; ++nc)
    #pragma unroll
    for (int j = 0; j < 4; ++j)
      out[(size_t)(b*S_ + q0w + g*4 + j)*E_ + h*64 + nc*16 + li] = f2bf(o[nc][j] * inv[j]);
}

extern "C" void kernel_launch(void* const* d_in, const int* in_sizes, int n_in,
                              void* d_out, int out_size, void* d_ws, size_t ws_size,
                              hipStream_t stream) {
  const float* x       = (const float*)d_in[0];
  const float* ln1g    = (const float*)d_in[1];
  const float* ln1b    = (const float*)d_in[2];
  const float* w_attn  = (const float*)d_in[3];
  const float* b_attn  = (const float*)d_in[4];
  const float* w_aproj = (const float*)d_in[5];
  const float* b_aproj = (const float*)d_in[6];
  const float* ln2g    = (const float*)d_in[7];
  const float* ln2b    = (const float*)d_in[8];
  const float* w_fc    = (const float*)d_in[9];
  const float* b_fc    = (const float*)d_in[10];
  const float* w_fproj = (const float*)d_in[11];
  const float* b_fproj = (const float*)d_in[12];
  float* out = (float*)d_out;

  char* ws = (char*)d_ws;
  unsigned short* h1       = (unsigned short*)(ws + 0);          // 4096x768 bf16
  unsigned short* qkv      = (unsigned short*)(ws + 6291456);    // 4096x2304 bf16
  unsigned short* attno    = (unsigned short*)(ws + 25165824);   // 4096x768 bf16
  float*          x2       = (float*)(ws + 31457280);            // 4096x768 f32
  unsigned short* h2       = (unsigned short*)(ws + 44040192);   // 4096x768 bf16
  unsigned short* h3       = (unsigned short*)(ws + 50331648);   // 4096x3072 bf16
  unsigned short* wt_attn  = (unsigned short*)(ws + 75497472);   // 2304x768 bf16
  unsigned short* wt_aproj = (unsigned short*)(ws + 79036416);   // 768x768
  unsigned short* wt_fc    = (unsigned short*)(ws + 80216064);   // 3072x768
  unsigned short* wt_fproj = (unsigned short*)(ws + 84934656);   // 768x3072
  unsigned short* vtg      = (unsigned short*)(ws + 89653248);   // 1536x2048 bf16 (V^T)

  // weight transpose+convert: [K][N] f32 -> [N][K] bf16
  tconv_kernel<<<dim3(2304/32,  768/32), 256, 0, stream>>>(w_attn,  wt_attn,  768, 2304);
  tconv_kernel<<<dim3( 768/32,  768/32), 256, 0, stream>>>(w_aproj, wt_aproj, 768,  768);
  tconv_kernel<<<dim3(3072/32,  768/32), 256, 0, stream>>>(w_fc,    wt_fc,    768, 3072);
  tconv_kernel<<<dim3( 768/32, 3072/32), 256, 0, stream>>>(w_fproj, wt_fproj, 3072, 768);

  // LN1
  ln_kernel<<<dim3(M_TOT), dim3(64), 0, stream>>>(x, ln1g, ln1b, h1);
  // QKV
  gemm_kernel<0><<<dim3(2304/128, M_TOT/128), 256, 0, stream>>>(h1, wt_attn, b_attn, nullptr, qkv, nullptr, M_TOT, 2304, 768);
  // V transpose for attention
  vtrans_kernel<<<dim3(S_/32, B_*H_*2), 256, 0, stream>>>(qkv, vtg);
  // attention
  attn_kernel<<<dim3(S_/64, B_*H_), dim3(256), 0, stream>>>(qkv, vtg, attno);
  // attn proj + residual -> x2 (f32)
  gemm_kernel<1><<<dim3(768/128, M_TOT/128), 256, 0, stream>>>(attno, wt_aproj, b_aproj, x, nullptr, x2, M_TOT, 768, 768);
  // LN2
  ln_kernel<<<dim3(M_TOT), dim3(64), 0, stream>>>(x2, ln2g, ln2b, h2);
  // FC + gelu
  gemm_kernel<2><<<dim3(3072/128, M_TOT/128), 256, 0, stream>>>(h2, wt_fc, b_fc, nullptr, h3, nullptr, M_TOT, 3072, 768);
  // fproj + residual -> out (f32)
  gemm_kernel<1><<<dim3(768/128, M_TOT/128), 256, 0, stream>>>(h3, wt_fproj, b_fproj, x2, nullptr, out, M_TOT, 768, 3072);
}